// Round 6
// baseline (233.988 us; speedup 1.0000x reference)
//
#include <hip/hip_runtime.h>
#include <hip/hip_bf16.h>

#define T_ALL 512
#define TB 16
#define NB (T_ALL / TB)
#define LOG2E 1.44269504088896f

typedef __attribute__((ext_vector_type(8))) short bf16x8;
typedef __attribute__((ext_vector_type(4))) float f32x4;

#define DPPF(v, CTRL) __uint_as_float((unsigned)__builtin_amdgcn_update_dpp(0, (int)__float_as_uint(v), (CTRL), 0xF, 0xF, true))

__device__ __forceinline__ unsigned pack2bf16(float a, float b) {
    unsigned ua = __float_as_uint(a), ub = __float_as_uint(b);
    ua += 0x7FFFu + ((ua >> 16) & 1u);   // RNE
    ub += 0x7FFFu + ((ub >> 16) & 1u);
    return (ua >> 16) | (ub & 0xFFFF0000u);
}
__device__ __forceinline__ bf16x8 make_frag(float4 lo, float4 hi) {
    union { unsigned u[4]; bf16x8 v; } r;
    r.u[0] = pack2bf16(lo.x, lo.y);
    r.u[1] = pack2bf16(lo.z, lo.w);
    r.u[2] = pack2bf16(hi.x, hi.y);
    r.u[3] = pack2bf16(hi.z, hi.w);
    return r.v;
}
__device__ __forceinline__ float4 scale4(float4 v, float s) {
    return make_float4(v.x * s, v.y * s, v.z * s, v.w * s);
}
__device__ __forceinline__ float2 pkfma(float2 a, float2 b, float2 c) {
    return make_float2(fmaf(a.x, b.x, c.x), fmaf(a.y, b.y, c.y));
}
__device__ __forceinline__ float sig2(float pre) {   // pre already log2e-scaled
    return __builtin_amdgcn_rcpf(1.0f + __builtin_amdgcn_exp2f(-pre));
}
__device__ __forceinline__ float tanh_c(float c) {
    return fmaf(2.0f, __builtin_amdgcn_rcpf(
        1.0f + __builtin_amdgcn_exp2f(-2.0f * LOG2E * c)), -1.0f);
}
__device__ __forceinline__ float fsigm(float x) {
    return __builtin_amdgcn_rcpf(1.0f + __builtin_amdgcn_exp2f(-LOG2E * x));
}

// 4 batch rows per wave; 512 blocks x 1 wave.
// Lane = (r = lane>>4: row-sub 0..3, j = lane&15: h-unit).
// LSTM1: lane computes all 4 gates of unit j (no cross-lane gate combine);
//        h1 broadcast via 1 ds_write + 4 broadcast ds_read_b128 per step.
// LSTM2 (lagged 1 step): 16 gates/row -> 1 gate/lane (m=(lane>>2)&3, Tq=lane&3),
//        quad DPP combine; h2 vector via tiny LDS roundtrip.
// xg via MFMA with A = permuted pre-scaled Wih1^T, B = x: each lane's acc[0..3]
// = gates i,f,g,o of (j = nt*4+kh, t = tl)  -> b128 write, b128 scan read.
__global__ __launch_bounds__(64, 1)
void lstm_fused_v6(const float* __restrict__ x,
        const float* __restrict__ Wih1, const float* __restrict__ Whh1,
        const float* __restrict__ bih1, const float* __restrict__ bhh1,
        const float* __restrict__ Wih2, const float* __restrict__ Whh2,
        const float* __restrict__ bih2, const float* __restrict__ bhh2,
        const float* __restrict__ Wfc,  const float* __restrict__ bfc,
        float* __restrict__ out)
{
    __shared__ __align__(16) float xs[4][TB][16][4];   // [row][t][j][gateT] 16 KB
    __shared__ __align__(16) float h1all[64];          // [row][j]
    __shared__ __align__(16) float xh2[64];            // [row][Tq][m]

    const int lane = threadIdx.x;
    const int tl = lane & 15;      // MFMA: C col (timestep) / A row
    const int kh = lane >> 4;      // MFMA: k-chunk
    const int jm = lane & 15;      // scan: h-unit j
    const int rr_ = lane >> 4;     // scan: row-sub
    const int m2 = (lane >> 2) & 3;
    const int Tq = lane & 3;

    // ---- A-frags: permuted Wih1 so C rows = gate slots (T=r4, j=nt*4+kh) ----
    // A row m=tl of tile nt -> gate (T = tl&3, j = nt*4 + (tl>>2))
    const int Ta = tl & 3, jA = tl >> 2;
    const float scA = (Ta == 2) ? 2.0f * LOG2E : LOG2E;
    bf16x8 wA[4][2];
#pragma unroll
    for (int nt = 0; nt < 4; ++nt)
#pragma unroll
        for (int kk = 0; kk < 2; ++kk) {
            const float* wp = Wih1 + (size_t)(Ta * 16 + nt * 4 + jA) * 64 + kk * 32 + kh * 8;
            wA[nt][kk] = make_frag(scale4(*(const float4*)wp, scA),
                                   scale4(*(const float4*)(wp + 4), scA));
        }
    f32x4 bias1v[4];
#pragma unroll
    for (int nt = 0; nt < 4; ++nt)
#pragma unroll
        for (int r4 = 0; r4 < 4; ++r4) {
            const int g = r4 * 16 + nt * 4 + kh;
            const float s = (r4 == 2) ? 2.0f * LOG2E : LOG2E;
            bias1v[nt][r4] = (bih1[g] + bhh1[g]) * s;
        }

    // ---- Whh1: all 4 gate rows of unit j, pre-scaled ----
    float2 w1[4][8];
#pragma unroll
    for (int T = 0; T < 4; ++T) {
        const float s = (T == 2) ? 2.0f * LOG2E : LOG2E;
        const float* wp = Whh1 + (size_t)(T * 16 + jm) * 16;
#pragma unroll
        for (int kk = 0; kk < 8; ++kk)
            w1[T][kk] = make_float2(wp[2 * kk] * s, wp[2 * kk + 1] * s);
    }

    // ---- LSTM2 weights: one gate per lane, row2 = Tq*4 + m2 ----
    const int row2 = Tq * 4 + m2;
    const float sc2 = (Tq == 2) ? 2.0f * LOG2E : LOG2E;
    const float aA2 = (Tq == 2) ? 2.0f : 1.0f, aB2 = (Tq == 2) ? -1.0f : 0.0f;
    float2 w2[8];
    {
        const float* wp = Wih2 + row2 * 16;
#pragma unroll
        for (int kk = 0; kk < 8; ++kk)
            w2[kk] = make_float2(wp[2 * kk] * sc2, wp[2 * kk + 1] * sc2);
    }
    float2 wh2[2];
    {
        const float* wp = Whh2 + row2 * 4;
        wh2[0] = make_float2(wp[0] * sc2, wp[1] * sc2);
        wh2[1] = make_float2(wp[2] * sc2, wp[3] * sc2);
    }
    const float bias2 = (bih2[row2] + bhh2[row2]) * sc2;

    const float4 wfc = *(const float4*)(Wfc + lane * 4);
    const float bfcv = bfc[lane];

    // ---- state ----
    float4 hq0 = {0,0,0,0}, hq1 = {0,0,0,0}, hq2 = {0,0,0,0}, hq3 = {0,0,0,0};
    float c1 = 0.f, c2 = 0.f, h2r = 0.f;
    f32x4 h2vec = {0.f, 0.f, 0.f, 0.f};

    const float* xbase = x + (size_t)blockIdx.x * 4 * T_ALL * 64;

    // ---- prefetch x block 0 (4 rows, frag-pattern addresses) ----
    float4 xpf[4][4];
#pragma unroll
    for (int rw = 0; rw < 4; ++rw)
#pragma unroll
        for (int kk = 0; kk < 2; ++kk)
#pragma unroll
            for (int hf = 0; hf < 2; ++hf)
                xpf[rw][kk * 2 + hf] = *(const float4*)(
                    xbase + (size_t)rw * (T_ALL * 64) + tl * 64 + kk * 32 + kh * 8 + hf * 4);

    for (int c = 0; c < NB; ++c) {
        // B-frags (x) for 4 rows
        bf16x8 xf[4][2];
#pragma unroll
        for (int rw = 0; rw < 4; ++rw) {
            xf[rw][0] = make_frag(xpf[rw][0], xpf[rw][1]);
            xf[rw][1] = make_frag(xpf[rw][2], xpf[rw][3]);
        }
        if (c + 1 < NB) {
            const float* src = xbase + (size_t)(c + 1) * (TB * 64);
#pragma unroll
            for (int rw = 0; rw < 4; ++rw)
#pragma unroll
                for (int kk = 0; kk < 2; ++kk)
#pragma unroll
                    for (int hf = 0; hf < 2; ++hf)
                        xpf[rw][kk * 2 + hf] = *(const float4*)(
                            src + (size_t)rw * (T_ALL * 64) + tl * 64 + kk * 32 + kh * 8 + hf * 4);
        }

        // 32 MFMAs: xg for 4 rows x 16 steps; b128 writes [row][t][j][0..3]
#pragma unroll
        for (int rw = 0; rw < 4; ++rw)
#pragma unroll
            for (int nt = 0; nt < 4; ++nt) {
                f32x4 acc = bias1v[nt];
                acc = __builtin_amdgcn_mfma_f32_16x16x32_bf16(wA[nt][0], xf[rw][0], acc, 0, 0, 0);
                acc = __builtin_amdgcn_mfma_f32_16x16x32_bf16(wA[nt][1], xf[rw][1], acc, 0, 0, 0);
                *(f32x4*)&xs[rw][tl][nt * 4 + kh][0] = acc;
            }

        // ---- sequential scan over 16 timesteps ----
#pragma unroll
        for (int tt = 0; tt < TB; ++tt) {
            const f32x4 xq = *(const f32x4*)&xs[rr_][tt][jm][0];
            const float2 hp0 = make_float2(hq0.x, hq0.y), hp1 = make_float2(hq0.z, hq0.w);
            const float2 hp2 = make_float2(hq1.x, hq1.y), hp3 = make_float2(hq1.z, hq1.w);
            const float2 hp4 = make_float2(hq2.x, hq2.y), hp5 = make_float2(hq2.z, hq2.w);
            const float2 hp6 = make_float2(hq3.x, hq3.y), hp7 = make_float2(hq3.z, hq3.w);

            // LSTM1: all 4 gate dots, lane-local
            float2 a0 = make_float2(xq[0], 0.f), a1 = make_float2(xq[1], 0.f);
            float2 a2 = make_float2(xq[2], 0.f), a3 = make_float2(xq[3], 0.f);
            a0 = pkfma(w1[0][0], hp0, a0); a1 = pkfma(w1[1][0], hp0, a1);
            a2 = pkfma(w1[2][0], hp0, a2); a3 = pkfma(w1[3][0], hp0, a3);
            a0 = pkfma(w1[0][1], hp1, a0); a1 = pkfma(w1[1][1], hp1, a1);
            a2 = pkfma(w1[2][1], hp1, a2); a3 = pkfma(w1[3][1], hp1, a3);
            a0 = pkfma(w1[0][2], hp2, a0); a1 = pkfma(w1[1][2], hp2, a1);
            a2 = pkfma(w1[2][2], hp2, a2); a3 = pkfma(w1[3][2], hp2, a3);
            a0 = pkfma(w1[0][3], hp3, a0); a1 = pkfma(w1[1][3], hp3, a1);
            a2 = pkfma(w1[2][3], hp3, a2); a3 = pkfma(w1[3][3], hp3, a3);
            a0 = pkfma(w1[0][4], hp4, a0); a1 = pkfma(w1[1][4], hp4, a1);
            a2 = pkfma(w1[2][4], hp4, a2); a3 = pkfma(w1[3][4], hp4, a3);
            a0 = pkfma(w1[0][5], hp5, a0); a1 = pkfma(w1[1][5], hp5, a1);
            a2 = pkfma(w1[2][5], hp5, a2); a3 = pkfma(w1[3][5], hp5, a3);
            a0 = pkfma(w1[0][6], hp6, a0); a1 = pkfma(w1[1][6], hp6, a1);
            a2 = pkfma(w1[2][6], hp6, a2); a3 = pkfma(w1[3][6], hp6, a3);
            a0 = pkfma(w1[0][7], hp7, a0); a1 = pkfma(w1[1][7], hp7, a1);
            a2 = pkfma(w1[2][7], hp7, a2); a3 = pkfma(w1[3][7], hp7, a3);

            const float act_i = sig2(a0.x + a0.y);
            const float act_f = sig2(a1.x + a1.y);
            const float act_g = fmaf(2.f, sig2(a2.x + a2.y), -1.f);
            const float act_o = sig2(a3.x + a3.y);
            c1 = fmaf(act_f, c1, act_i * act_g);
            const float h1v = act_o * tanh_c(c1);

            // broadcast h1(t): 1 write + 4 broadcast b128 reads (consumed next step)
            h1all[lane] = h1v;
            const float4 t0 = *(const float4*)&h1all[rr_ * 16 + 0];
            const float4 t1 = *(const float4*)&h1all[rr_ * 16 + 4];
            const float4 t2 = *(const float4*)&h1all[rr_ * 16 + 8];
            const float4 t3 = *(const float4*)&h1all[rr_ * 16 + 12];

            // ---- LSTM2 step t-1 (old hq -> relu, h2vec = h2(t-2)); fills latency ----
            float2 acc2 = make_float2(bias2, 0.f);
            acc2 = pkfma(w2[0], make_float2(fmaxf(hp0.x, 0.f), fmaxf(hp0.y, 0.f)), acc2);
            acc2 = pkfma(w2[1], make_float2(fmaxf(hp1.x, 0.f), fmaxf(hp1.y, 0.f)), acc2);
            acc2 = pkfma(w2[2], make_float2(fmaxf(hp2.x, 0.f), fmaxf(hp2.y, 0.f)), acc2);
            acc2 = pkfma(w2[3], make_float2(fmaxf(hp3.x, 0.f), fmaxf(hp3.y, 0.f)), acc2);
            acc2 = pkfma(w2[4], make_float2(fmaxf(hp4.x, 0.f), fmaxf(hp4.y, 0.f)), acc2);
            acc2 = pkfma(w2[5], make_float2(fmaxf(hp5.x, 0.f), fmaxf(hp5.y, 0.f)), acc2);
            acc2 = pkfma(w2[6], make_float2(fmaxf(hp6.x, 0.f), fmaxf(hp6.y, 0.f)), acc2);
            acc2 = pkfma(w2[7], make_float2(fmaxf(hp7.x, 0.f), fmaxf(hp7.y, 0.f)), acc2);
            acc2 = pkfma(wh2[0], make_float2(h2vec[0], h2vec[1]), acc2);
            acc2 = pkfma(wh2[1], make_float2(h2vec[2], h2vec[3]), acc2);
            const float p2 = acc2.x + acc2.y;
            const float act2 = fmaf(aA2, sig2(p2), aB2);
            const float iv = DPPF(act2, 0x00);   // quad slot 0 = i
            const float fv = DPPF(act2, 0x55);   // slot 1 = f
            const float gv = DPPF(act2, 0xAA);   // slot 2 = g
            const float ov = DPPF(act2, 0xFF);   // slot 3 = o
            const float c2n = fmaf(fv, c2, iv * gv);
            const float h2n = ov * tanh_c(c2n);
            if (!((c == 0) && (tt == 0))) { c2 = c2n; h2r = h2n; }
            xh2[(rr_ << 4) + (Tq << 2) + m2] = h2r;
            h2vec = *(const f32x4*)&xh2[(rr_ << 4) + (Tq << 2)];

            hq0 = t0; hq1 = t1; hq2 = t2; hq3 = t3;
        }
    }

    // ---- drain: LSTM2 step 511 (hq = h(511), h2vec = h2(510)) ----
    {
        float2 acc2 = make_float2(bias2, 0.f);
        acc2 = pkfma(w2[0], make_float2(fmaxf(hq0.x, 0.f), fmaxf(hq0.y, 0.f)), acc2);
        acc2 = pkfma(w2[1], make_float2(fmaxf(hq0.z, 0.f), fmaxf(hq0.w, 0.f)), acc2);
        acc2 = pkfma(w2[2], make_float2(fmaxf(hq1.x, 0.f), fmaxf(hq1.y, 0.f)), acc2);
        acc2 = pkfma(w2[3], make_float2(fmaxf(hq1.z, 0.f), fmaxf(hq1.w, 0.f)), acc2);
        acc2 = pkfma(w2[4], make_float2(fmaxf(hq2.x, 0.f), fmaxf(hq2.y, 0.f)), acc2);
        acc2 = pkfma(w2[5], make_float2(fmaxf(hq2.z, 0.f), fmaxf(hq2.w, 0.f)), acc2);
        acc2 = pkfma(w2[6], make_float2(fmaxf(hq3.x, 0.f), fmaxf(hq3.y, 0.f)), acc2);
        acc2 = pkfma(w2[7], make_float2(fmaxf(hq3.z, 0.f), fmaxf(hq3.w, 0.f)), acc2);
        acc2 = pkfma(wh2[0], make_float2(h2vec[0], h2vec[1]), acc2);
        acc2 = pkfma(wh2[1], make_float2(h2vec[2], h2vec[3]), acc2);
        const float p2 = acc2.x + acc2.y;
        const float act2 = fmaf(aA2, sig2(p2), aB2);
        const float iv = DPPF(act2, 0x00);
        const float fv = DPPF(act2, 0x55);
        const float gv = DPPF(act2, 0xAA);
        const float ov = DPPF(act2, 0xFF);
        c2 = fmaf(fv, c2, iv * gv);
        h2r = ov * tanh_c(c2);
        xh2[(rr_ << 4) + (Tq << 2) + m2] = h2r;
    }

    // ---- FC + sigmoid: 4 rows x 64 outputs; lane = output dim d ----
#pragma unroll
    for (int rw = 0; rw < 4; ++rw) {
        const float4 hv = *(const float4*)&xh2[rw * 16];   // [rw][Tq=0][0..3]
        float acc = bfcv;
        acc = fmaf(wfc.x, hv.x, acc);
        acc = fmaf(wfc.y, hv.y, acc);
        acc = fmaf(wfc.z, hv.z, acc);
        acc = fmaf(wfc.w, hv.w, acc);
        out[((size_t)blockIdx.x * 4 + rw) * 64 + lane] = fsigm(acc);
    }
}

extern "C" void kernel_launch(void* const* d_in, const int* in_sizes, int n_in,
                              void* d_out, int out_size, void* d_ws, size_t ws_size,
                              hipStream_t stream) {
    const float* x    = (const float*)d_in[0];
    const float* Wih1 = (const float*)d_in[1];
    const float* Whh1 = (const float*)d_in[2];
    const float* bih1 = (const float*)d_in[3];
    const float* bhh1 = (const float*)d_in[4];
    const float* Wih2 = (const float*)d_in[5];
    const float* Whh2 = (const float*)d_in[6];
    const float* bih2 = (const float*)d_in[7];
    const float* bhh2 = (const float*)d_in[8];
    const float* Wfc  = (const float*)d_in[9];
    const float* bfc  = (const float*)d_in[10];
    float* out = (float*)d_out;

    lstm_fused_v6<<<dim3(512), dim3(64), 0, stream>>>(
        x, Wih1, Whh1, bih1, bhh1, Wih2, Whh2, bih2, bhh2, Wfc, bfc, out);
}

// Round 7
// 190.230 us; speedup vs baseline: 1.2300x; 1.2300x over previous
//
#include <hip/hip_runtime.h>
#include <hip/hip_bf16.h>

#define T_ALL 512
#define TB 16
#define NB (T_ALL / TB)
#define LOG2E 1.44269504088896f
#define XSTR 68   // padded xg row stride (floats): kh-write conflicts 4-way -> 2-way (free)

typedef __attribute__((ext_vector_type(8))) short bf16x8;
typedef __attribute__((ext_vector_type(4))) float f32x4;

#define DPPF(v, CTRL) __uint_as_float((unsigned)__builtin_amdgcn_update_dpp(0, (int)__float_as_uint(v), (CTRL), 0xF, 0xF, true))
#define BPERM(a, v)   __uint_as_float((unsigned)__builtin_amdgcn_ds_bpermute((a), (int)__float_as_uint(v)))

__device__ __forceinline__ unsigned pack2bf16(float a, float b) {
    unsigned ua = __float_as_uint(a), ub = __float_as_uint(b);
    ua += 0x7FFFu + ((ua >> 16) & 1u);   // RNE
    ub += 0x7FFFu + ((ub >> 16) & 1u);
    return (ua >> 16) | (ub & 0xFFFF0000u);
}
__device__ __forceinline__ bf16x8 make_frag(float4 lo, float4 hi) {
    union { unsigned u[4]; bf16x8 v; } r;
    r.u[0] = pack2bf16(lo.x, lo.y);
    r.u[1] = pack2bf16(lo.z, lo.w);
    r.u[2] = pack2bf16(hi.x, hi.y);
    r.u[3] = pack2bf16(hi.z, hi.w);
    return r.v;
}
__device__ __forceinline__ float4 scale4(float4 v, float s) {
    return make_float4(v.x * s, v.y * s, v.z * s, v.w * s);
}
__device__ __forceinline__ float2 pkfma(float2 a, float2 b, float2 c) {
    return make_float2(fmaf(a.x, b.x, c.x), fmaf(a.y, b.y, c.y));
}
__device__ __forceinline__ float tanh_c(float c) {
    return fmaf(2.0f, __builtin_amdgcn_rcpf(
        1.0f + __builtin_amdgcn_exp2f(-2.0f * LOG2E * c)), -1.0f);
}
__device__ __forceinline__ float fsigm(float x) {
    return __builtin_amdgcn_rcpf(1.0f + __builtin_amdgcn_exp2f(-LOG2E * x));
}

// One wave per batch row (2048 waves = 2/SIMD). Software-pipelined scan:
// each iteration t runs ONE batched trans phase {tanh(c1(t-1)) lanes 0-15 |
// sigmoid/tanh(p2(t-2)) lanes 16-31} (2 trans ops total), then forms h1(t-1),
// gathers it (4 bperm), does LSTM1 step t (pair-packed butterfly dot, 2 trans),
// LSTM2 state update for t-2 (+2 trans for tanh(c2)), and p2(t-1) formation.
// 6 trans/step vs v5's 8; no per-step guards (zero-init self-heals; one p2b=0
// override after t=0). xg (pre-scaled gate preacts) via MFMA into padded LDS.
__global__ __launch_bounds__(64, 2)
void lstm_fused_v7(const float* __restrict__ x,
        const float* __restrict__ Wih1, const float* __restrict__ Whh1,
        const float* __restrict__ bih1, const float* __restrict__ bhh1,
        const float* __restrict__ Wih2, const float* __restrict__ Whh2,
        const float* __restrict__ bih2, const float* __restrict__ bhh2,
        const float* __restrict__ Wfc,  const float* __restrict__ bfc,
        float* __restrict__ out)
{
    __shared__ __align__(16) float xs[TB * XSTR];

    const int lane = threadIdx.x;
    const int tl = lane & 15;     // MFMA: A row (timestep) / C col
    const int kh = lane >> 4;     // MFMA: k-group
    const size_t b = blockIdx.x;

    const int T1 = lane & 3;      // LSTM1 gate type AND k-slice
    const int j1 = lane >> 2;     // LSTM1 h-unit

    // ---- per-lane activation constants ----
    const float aA1 = (T1 == 2) ? 2.0f : 1.0f, aB1 = (T1 == 2) ? -1.0f : 0.0f;
    const bool lo16 = (lane < 16);
    const float esc = lo16 ? (-2.0f * LOG2E) : -1.0f;     // batch exp2 scale
    const bool bt = lo16 || ((lane & 3) == 2);            // tanh-affine lanes
    const float aAb = bt ? 2.0f : 1.0f, aBb = bt ? -1.0f : 0.0f;

    // ---- B fragments for xg MFMA: Wih1^T, pre-scaled per gate block ----
    bf16x8 wb[4][2];
    float bias1[4];
#pragma unroll
    for (int n = 0; n < 4; ++n) {
        const float scn = (n == 2) ? 2.0f * LOG2E : LOG2E;
#pragma unroll
        for (int kk = 0; kk < 2; ++kk) {
            const float* wp = Wih1 + (size_t)(n * 16 + tl) * 64 + kk * 32 + kh * 8;
            wb[n][kk] = make_frag(scale4(*(const float4*)wp, scn),
                                  scale4(*(const float4*)(wp + 4), scn));
        }
        bias1[n] = (bih1[n * 16 + tl] + bhh1[n * 16 + tl]) * scn;
    }

    // ---- LSTM1 butterfly weights, pair-packed along k (rows T,T^2,T^1,T^3) ----
    float2 wrA0, wrA1, wrB0, wrB1, wrC0, wrC1, wrD0, wrD1;
    {
        const float sA = (T1 == 2) ? 2.0f * LOG2E : LOG2E;
        const float sB = ((T1 ^ 2) == 2) ? 2.0f * LOG2E : LOG2E;
        const float sC = ((T1 ^ 1) == 2) ? 2.0f * LOG2E : LOG2E;
        const float sD = ((T1 ^ 3) == 2) ? 2.0f * LOG2E : LOG2E;
        const float4 wa  = scale4(*(const float4*)(Whh1 + ((T1    ) * 16 + j1) * 16 + 4 * T1), sA);
        const float4 wbv = scale4(*(const float4*)(Whh1 + ((T1 ^ 2) * 16 + j1) * 16 + 4 * T1), sB);
        const float4 wc  = scale4(*(const float4*)(Whh1 + ((T1 ^ 1) * 16 + j1) * 16 + 4 * T1), sC);
        const float4 wd  = scale4(*(const float4*)(Whh1 + ((T1 ^ 3) * 16 + j1) * 16 + 4 * T1), sD);
        wrA0 = make_float2(wa.x, wa.y);   wrA1 = make_float2(wa.z, wa.w);
        wrB0 = make_float2(wbv.x, wbv.y); wrB1 = make_float2(wbv.z, wbv.w);
        wrC0 = make_float2(wc.x, wc.y);   wrC1 = make_float2(wc.z, wc.w);
        wrD0 = make_float2(wd.x, wd.y);   wrD1 = make_float2(wd.z, wd.w);
    }

    // ---- LSTM2 weights: gate row2 = T2*4+m2, k-slice 4*T1..+3 (v5 mapping) ----
    const int m2 = lane >> 4;
    const int T2 = (lane >> 2) & 3;
    const int row2 = T2 * 4 + m2;
    const float sc2 = (T2 == 2) ? 2.0f * LOG2E : LOG2E;
    const float4 w2q = scale4(*(const float4*)(Wih2 + row2 * 16 + 4 * T1), sc2);
    const float2 w2a = make_float2(w2q.x, w2q.y);
    const float2 w2b = make_float2(w2q.z, w2q.w);
    const float w2h = Whh2[row2 * 4 + T1] * sc2;
    const float bias2l = (T1 == 0) ? (bih2[row2] + bhh2[row2]) * sc2 : 0.0f;

    const float4 wfc = *(const float4*)(Wfc + lane * 4);
    const float bfcv = bfc[lane];

    // ---- hoisted bpermute addresses (bytes = srclane*4) ----
    const int ag0 = (4 * T1 + 0) << 2;                 // h1[4T+u] from lane 4T+u
    const int ag1 = (4 * T1 + 1) << 2;
    const int ag2 = (4 * T1 + 2) << 2;
    const int ag3 = (4 * T1 + 3) << 2;
    const int ac1 = (4 * (lane & 15)) << 2;            // c1 of unit j from lane 4j
    const int ao1 = ((4 * (lane & 15)) + 3) << 2;      // o-act of unit j from lane 4j+3
    const int ah2 = (16 + 4 * (lane & 3)) << 2;        // h2[s] from quad 4+s
    const int ap2 = (16 * ((lane >> 2) & 3) + 4 * (lane & 3)) << 2;  // p2 of gate(T,m)

    const int gidx = T1 * 16 + j1;                     // this lane's gate column in xg

    // ---- pipeline state ----
    float c1r = 0.f;   // c1(t-1), quad-replicated
    float c1b = 0.f;   // bperm'd c1(t-1) on lane j
    float o1b = 0.f;   // bperm'd o-act(t-1) on lane j
    float p2b = 0.f;   // bperm'd p2(t-2) on lanes 16+4m+T
    float c2q = 0.f;   // c2(t-3 -> t-2), quad 4+m replicated
    float h2r = 0.f;   // h2(t-2) on lanes 16-31

#define STEP(XU) do { \
    const float _vb = lo16 ? c1b : p2b; \
    const float _e = __builtin_amdgcn_exp2f(esc * _vb); \
    const float _sb = __builtin_amdgcn_rcpf(1.0f + _e); \
    const float _outB = fmaf(aAb, _sb, aBb);            /* th1(t-1) | act2(t-2) */ \
    const float _h1 = o1b * _outB;                      /* h1(t-1), lanes 0-15 */ \
    const float _g0 = BPERM(ag0, _h1); \
    const float _g1 = BPERM(ag1, _h1); \
    const float _g2 = BPERM(ag2, _h1); \
    const float _g3 = BPERM(ag3, _h1); \
    const float2 _g01 = make_float2(_g0, _g1); \
    const float2 _g23 = make_float2(_g2, _g3); \
    float2 _aA = pkfma(wrA0, _g01, make_float2((XU), 0.f)); _aA = pkfma(wrA1, _g23, _aA); \
    float2 _aB = pkfma(wrB0, _g01, make_float2(0.f, 0.f)); _aB = pkfma(wrB1, _g23, _aB); \
    float2 _aC = pkfma(wrC0, _g01, make_float2(0.f, 0.f)); _aC = pkfma(wrC1, _g23, _aC); \
    float2 _aD = pkfma(wrD0, _g01, make_float2(0.f, 0.f)); _aD = pkfma(wrD1, _g23, _aD); \
    const float _sA = _aA.x + _aA.y, _sB2 = _aB.x + _aB.y; \
    const float _sC = _aC.x + _aC.y, _sD = _aD.x + _aD.y; \
    const float _u0 = _sA + DPPF(_sC, 0xB1); \
    const float _u1 = _sB2 + DPPF(_sD, 0xB1); \
    const float _pre = _u0 + DPPF(_u1, 0x4E); \
    const float _s1 = __builtin_amdgcn_rcpf(1.0f + __builtin_amdgcn_exp2f(-_pre)); \
    const float _act = fmaf(aA1, _s1, aB1);             /* act(t), gate (T,j) */ \
    const float _iv = DPPF(_act, 0x00); \
    const float _fv = DPPF(_act, 0x55); \
    const float _gv = DPPF(_act, 0xAA); \
    c1r = fmaf(_fv, c1r, _iv * _gv);                    /* c1(t) */ \
    c1b = BPERM(ac1, c1r); \
    o1b = BPERM(ao1, _act); \
    { \
        const float _i2 = DPPF(_outB, 0x00); \
        const float _f2 = DPPF(_outB, 0x55); \
        const float _g2v = DPPF(_outB, 0xAA); \
        const float _o2 = DPPF(_outB, 0xFF); \
        c2q = fmaf(_f2, c2q, _i2 * _g2v);               /* c2(t-2) */ \
        h2r = _o2 * tanh_c(c2q);                        /* h2(t-2) */ \
    } \
    const float _h2s = BPERM(ah2, h2r); \
    const float2 _r01 = make_float2(fmaxf(_g01.x, 0.f), fmaxf(_g01.y, 0.f)); \
    const float2 _r23 = make_float2(fmaxf(_g23.x, 0.f), fmaxf(_g23.y, 0.f)); \
    float2 _a2 = pkfma(w2a, _r01, make_float2(bias2l, w2h * _h2s)); \
    _a2 = pkfma(w2b, _r23, _a2); \
    float _p2 = _a2.x + _a2.y; \
    _p2 += DPPF(_p2, 0xB1); \
    _p2 += DPPF(_p2, 0x4E);                             /* p2(t-1), quad-repl */ \
    p2b = BPERM(ap2, _p2); \
} while (0)

    const float* xb = x + b * (size_t)(T_ALL * 64);

    // ---- prefetch x chunk 0 ----
    float4 xpf[4];
#pragma unroll
    for (int kk = 0; kk < 2; ++kk)
#pragma unroll
        for (int hf = 0; hf < 2; ++hf)
            xpf[kk * 2 + hf] = *(const float4*)(xb + tl * 64 + kk * 32 + kh * 8 + hf * 4);

    for (int c = 0; c < NB; ++c) {
        bf16x8 a0 = make_frag(xpf[0], xpf[1]);
        bf16x8 a1 = make_frag(xpf[2], xpf[3]);
        if (c + 1 < NB) {
            const float* src = xb + (size_t)(c + 1) * (TB * 64);
#pragma unroll
            for (int kk = 0; kk < 2; ++kk)
#pragma unroll
                for (int hf = 0; hf < 2; ++hf)
                    xpf[kk * 2 + hf] = *(const float4*)(src + tl * 64 + kk * 32 + kh * 8 + hf * 4);
        }

        // xg[t*XSTR + g] (pre-scaled, bias-folded) via 8 MFMAs
#pragma unroll
        for (int n = 0; n < 4; ++n) {
            f32x4 acc = {bias1[n], bias1[n], bias1[n], bias1[n]};
            acc = __builtin_amdgcn_mfma_f32_16x16x32_bf16(a0, wb[n][0], acc, 0, 0, 0);
            acc = __builtin_amdgcn_mfma_f32_16x16x32_bf16(a1, wb[n][1], acc, 0, 0, 0);
#pragma unroll
            for (int r = 0; r < 4; ++r)
                xs[(kh * 4 + r) * XSTR + n * 16 + tl] = acc[r];
        }

        // ---- sequential scan over 16 timesteps ----
        if (c == 0) {
            STEP(xs[0 * XSTR + gidx]);
            p2b = 0.f;   // squash p2(-1): keeps c2/h2 exactly zero until real data
#pragma unroll
            for (int tt = 1; tt < TB; ++tt)
                STEP(xs[tt * XSTR + gidx]);
        } else {
#pragma unroll
            for (int tt = 0; tt < TB; ++tt)
                STEP(xs[tt * XSTR + gidx]);
        }
    }

    // ---- drain-1 (pseudo-iteration 512): finishes h1(511), c2(510), p2(511) ----
    STEP(0.0f);

    // ---- drain-2: act2(511) -> c2(511) -> h2(511) ----
    {
        const float e2 = __builtin_amdgcn_exp2f(-p2b);
        const float sb2 = __builtin_amdgcn_rcpf(1.0f + e2);
        const float outB2 = fmaf(aAb, sb2, aBb);        // act2(511), lanes 16-31
        const float i2 = DPPF(outB2, 0x00);
        const float f2 = DPPF(outB2, 0x55);
        const float g2v = DPPF(outB2, 0xAA);
        const float o2 = DPPF(outB2, 0xFF);
        c2q = fmaf(f2, c2q, i2 * g2v);
        const float h2f = o2 * tanh_c(c2q);             // h2(511) on quad 4+m

        const float hm0 = __shfl(h2f, 16);
        const float hm1 = __shfl(h2f, 20);
        const float hm2 = __shfl(h2f, 24);
        const float hm3 = __shfl(h2f, 28);
        float accf = bfcv;
        accf = fmaf(wfc.x, hm0, accf);
        accf = fmaf(wfc.y, hm1, accf);
        accf = fmaf(wfc.z, hm2, accf);
        accf = fmaf(wfc.w, hm3, accf);
        out[b * 64 + lane] = fsigm(accf);
    }
#undef STEP
}

extern "C" void kernel_launch(void* const* d_in, const int* in_sizes, int n_in,
                              void* d_out, int out_size, void* d_ws, size_t ws_size,
                              hipStream_t stream) {
    const float* x    = (const float*)d_in[0];
    const float* Wih1 = (const float*)d_in[1];
    const float* Whh1 = (const float*)d_in[2];
    const float* bih1 = (const float*)d_in[3];
    const float* bhh1 = (const float*)d_in[4];
    const float* Wih2 = (const float*)d_in[5];
    const float* Whh2 = (const float*)d_in[6];
    const float* bih2 = (const float*)d_in[7];
    const float* bhh2 = (const float*)d_in[8];
    const float* Wfc  = (const float*)d_in[9];
    const float* bfc  = (const float*)d_in[10];
    float* out = (float*)d_out;

    lstm_fused_v7<<<dim3(2048), dim3(64), 0, stream>>>(
        x, Wih1, Whh1, bih1, bhh1, Wih2, Whh2, bih2, bhh2, Wfc, bfc, out);
}

// Round 8
// 161.275 us; speedup vs baseline: 1.4509x; 1.1795x over previous
//
#include <hip/hip_runtime.h>
#include <hip/hip_bf16.h>

#define T_ALL 512
#define TB 16
#define NB (T_ALL / TB)
#define LOG2E 1.44269504088896f
#define XSTR 68   // padded xg row stride (floats)

typedef __attribute__((ext_vector_type(8))) short bf16x8;
typedef __attribute__((ext_vector_type(4))) float f32x4;

#define DPPF(v, CTRL) __uint_as_float((unsigned)__builtin_amdgcn_update_dpp(0, (int)__float_as_uint(v), (CTRL), 0xF, 0xF, true))
#define SWZF(v, PAT)  __uint_as_float((unsigned)__builtin_amdgcn_ds_swizzle((int)__float_as_uint(v), (PAT)))
#define BPERM(a, v)   __uint_as_float((unsigned)__builtin_amdgcn_ds_bpermute((a), (int)__float_as_uint(v)))

__device__ __forceinline__ unsigned pack2bf16(float a, float b) {
    unsigned ua = __float_as_uint(a), ub = __float_as_uint(b);
    ua += 0x7FFFu + ((ua >> 16) & 1u);   // RNE
    ub += 0x7FFFu + ((ub >> 16) & 1u);
    return (ua >> 16) | (ub & 0xFFFF0000u);
}
__device__ __forceinline__ bf16x8 make_frag(float4 lo, float4 hi) {
    union { unsigned u[4]; bf16x8 v; } r;
    r.u[0] = pack2bf16(lo.x, lo.y);
    r.u[1] = pack2bf16(lo.z, lo.w);
    r.u[2] = pack2bf16(hi.x, hi.y);
    r.u[3] = pack2bf16(hi.z, hi.w);
    return r.v;
}
__device__ __forceinline__ float4 scale4(float4 v, float s) {
    return make_float4(v.x * s, v.y * s, v.z * s, v.w * s);
}
__device__ __forceinline__ float2 pkfma(float2 a, float2 b, float2 c) {
    return make_float2(fmaf(a.x, b.x, c.x), fmaf(a.y, b.y, c.y));
}
__device__ __forceinline__ float tanh_c(float c) {
    return fmaf(2.0f, __builtin_amdgcn_rcpf(
        1.0f + __builtin_amdgcn_exp2f(-2.0f * LOG2E * c)), -1.0f);
}
__device__ __forceinline__ float fsigm(float x) {
    return __builtin_amdgcn_rcpf(1.0f + __builtin_amdgcn_exp2f(-LOG2E * x));
}

// Wave-specialized: 1 row per 128-thread block (2048 blocks = 4 waves/SIMD).
// Wave0: LSTM1 recurrence only. lane = 4*j1 + T1; butterfly dot (rows
//   T,T^2,T^1,T^3 pre-permuted, pair-packed) + 2 DPP xor-adds; h1 valid on
//   lanes 4j (T1==0); next-step gather via 4 reg-bpermute (no LDS roundtrip).
//   Writes relu-input h1 chunk ring for wave1.
// Wave1: MFMA xg for chunk c+1 (pre-scaled Wih1^T, bias-folded, double-buffered
//   LDS) + x prefetch + LSTM2 scan of chunk c-1 (v5 mapping: lane=16m+4T+s,
//   quad DPP allreduce + 3 swizzle gate-combine) + final FC/sigmoid/store.
// One __syncthreads per 16-step chunk.
__global__ __launch_bounds__(128, 4)
void lstm_fused_v8(const float* __restrict__ x,
        const float* __restrict__ Wih1, const float* __restrict__ Whh1,
        const float* __restrict__ bih1, const float* __restrict__ bhh1,
        const float* __restrict__ Wih2, const float* __restrict__ Whh2,
        const float* __restrict__ bih2, const float* __restrict__ bhh2,
        const float* __restrict__ Wfc,  const float* __restrict__ bfc,
        float* __restrict__ out)
{
    __shared__ __align__(16) float xgl[2][TB * XSTR];   // xg double buffer
    __shared__ __align__(16) float h1l[2][TB][16];      // h1 chunk ring

    const int tid = threadIdx.x;
    const int wid = tid >> 6;
    const int lane = tid & 63;
    const size_t b = blockIdx.x;

    const int tl = lane & 15;     // MFMA: A row (timestep) / C col
    const int kh = lane >> 4;     // MFMA: k-group
    const int T1 = lane & 3;      // LSTM1 gate type AND k-slice
    const int j1 = lane >> 2;     // LSTM1 h-unit

    const float aA1 = (T1 == 2) ? 2.0f : 1.0f, aB1 = (T1 == 2) ? -1.0f : 0.0f;

    // ---- MFMA B-frags: Wih1^T pre-scaled per gate block (wave1 uses) ----
    bf16x8 wb[4][2];
    float bias1[4];
#pragma unroll
    for (int n = 0; n < 4; ++n) {
        const float scn = (n == 2) ? 2.0f * LOG2E : LOG2E;
#pragma unroll
        for (int kk = 0; kk < 2; ++kk) {
            const float* wp = Wih1 + (size_t)(n * 16 + tl) * 64 + kk * 32 + kh * 8;
            wb[n][kk] = make_frag(scale4(*(const float4*)wp, scn),
                                  scale4(*(const float4*)(wp + 4), scn));
        }
        bias1[n] = (bih1[n * 16 + tl] + bhh1[n * 16 + tl]) * scn;
    }

    // ---- LSTM1 butterfly weights, pair-packed (wave0 uses) ----
    float2 wrA0, wrA1, wrB0, wrB1, wrC0, wrC1, wrD0, wrD1;
    {
        const float sA = (T1 == 2) ? 2.0f * LOG2E : LOG2E;
        const float sB = ((T1 ^ 2) == 2) ? 2.0f * LOG2E : LOG2E;
        const float sC = ((T1 ^ 1) == 2) ? 2.0f * LOG2E : LOG2E;
        const float sD = ((T1 ^ 3) == 2) ? 2.0f * LOG2E : LOG2E;
        const float4 wa  = scale4(*(const float4*)(Whh1 + ((T1    ) * 16 + j1) * 16 + 4 * T1), sA);
        const float4 wbv = scale4(*(const float4*)(Whh1 + ((T1 ^ 2) * 16 + j1) * 16 + 4 * T1), sB);
        const float4 wc  = scale4(*(const float4*)(Whh1 + ((T1 ^ 1) * 16 + j1) * 16 + 4 * T1), sC);
        const float4 wd  = scale4(*(const float4*)(Whh1 + ((T1 ^ 3) * 16 + j1) * 16 + 4 * T1), sD);
        wrA0 = make_float2(wa.x, wa.y);   wrA1 = make_float2(wa.z, wa.w);
        wrB0 = make_float2(wbv.x, wbv.y); wrB1 = make_float2(wbv.z, wbv.w);
        wrC0 = make_float2(wc.x, wc.y);   wrC1 = make_float2(wc.z, wc.w);
        wrD0 = make_float2(wd.x, wd.y);   wrD1 = make_float2(wd.z, wd.w);
    }

    // ---- LSTM2 weights (wave1 uses): lane = 16*m2 + 4*T2 + s2 ----
    const int m2 = lane >> 4;
    const int T2 = (lane >> 2) & 3;
    const int s2 = lane & 3;
    const int row2 = T2 * 4 + m2;
    const float sc2 = (T2 == 2) ? 2.0f * LOG2E : LOG2E;
    const float aA2 = (T2 == 2) ? 2.0f : 1.0f, aB2 = (T2 == 2) ? -1.0f : 0.0f;
    const float4 w2q = scale4(*(const float4*)(Wih2 + row2 * 16 + 4 * s2), sc2);
    const float2 w2a = make_float2(w2q.x, w2q.y);
    const float2 w2b = make_float2(w2q.z, w2q.w);
    const float w2h = Whh2[row2 * 4 + s2] * sc2;
    const float bias2l = (s2 == 0) ? (bih2[row2] + bhh2[row2]) * sc2 : 0.0f;
    const float4 wfc = *(const float4*)(Wfc + lane * 4);
    const float bfcv = bfc[lane];

    // ---- cross-lane addresses ----
    const int ag0 = (16 * T1 + 0)  << 2;   // h[4T+0] from lane 16T+0
    const int ag1 = (16 * T1 + 4)  << 2;
    const int ag2 = (16 * T1 + 8)  << 2;
    const int ag3 = (16 * T1 + 12) << 2;
    const int ahs = s2 << 6;               // h2[s] from lane 16s
    const int gidx = T1 * 16 + j1;         // wave0's gate column in xg

    float c1r = 0.f, h1r = 0.f;            // wave0 state (valid on lanes 4j)
    float c2r = 0.f, h2v = 0.f, h2s = 0.f; // wave1 LSTM2 state

    const float* xb = x + b * (size_t)(T_ALL * 64);
    float4 xpf[4];
    const float2 zero2 = make_float2(0.f, 0.f);

#define LOADX(CH) do { \
    const float* _src = xb + (size_t)(CH) * (TB * 64); \
    _Pragma("unroll") \
    for (int _kk = 0; _kk < 2; ++_kk) \
        _Pragma("unroll") \
        for (int _hf = 0; _hf < 2; ++_hf) \
            xpf[_kk * 2 + _hf] = *(const float4*)(_src + tl * 64 + _kk * 32 + kh * 8 + _hf * 4); \
} while (0)

#define MFMA_XG(BUF) do { \
    bf16x8 _a0 = make_frag(xpf[0], xpf[1]); \
    bf16x8 _a1 = make_frag(xpf[2], xpf[3]); \
    _Pragma("unroll") \
    for (int _n = 0; _n < 4; ++_n) { \
        f32x4 _acc = {bias1[_n], bias1[_n], bias1[_n], bias1[_n]}; \
        _acc = __builtin_amdgcn_mfma_f32_16x16x32_bf16(_a0, wb[_n][0], _acc, 0, 0, 0); \
        _acc = __builtin_amdgcn_mfma_f32_16x16x32_bf16(_a1, wb[_n][1], _acc, 0, 0, 0); \
        _Pragma("unroll") \
        for (int _r = 0; _r < 4; ++_r) \
            xgl[BUF][(kh * 4 + _r) * XSTR + _n * 16 + tl] = _acc[_r]; \
    } \
} while (0)

#define STEP1(XU) do { \
    const float _g0 = BPERM(ag0, h1r); \
    const float _g1 = BPERM(ag1, h1r); \
    const float _g2 = BPERM(ag2, h1r); \
    const float _g3 = BPERM(ag3, h1r); \
    const float2 _g01 = make_float2(_g0, _g1); \
    const float2 _g23 = make_float2(_g2, _g3); \
    float2 _aA = pkfma(wrA0, _g01, make_float2((XU), 0.f)); _aA = pkfma(wrA1, _g23, _aA); \
    float2 _aB = pkfma(wrB0, _g01, zero2); _aB = pkfma(wrB1, _g23, _aB); \
    float2 _aC = pkfma(wrC0, _g01, zero2); _aC = pkfma(wrC1, _g23, _aC); \
    float2 _aD = pkfma(wrD0, _g01, zero2); _aD = pkfma(wrD1, _g23, _aD); \
    const float _sA = _aA.x + _aA.y, _sB2 = _aB.x + _aB.y; \
    const float _sC = _aC.x + _aC.y, _sD = _aD.x + _aD.y; \
    const float _u0 = _sA + DPPF(_sC, 0xB1); \
    const float _u1 = _sB2 + DPPF(_sD, 0xB1); \
    const float _pre = _u0 + DPPF(_u1, 0x4E); \
    const float _s1 = __builtin_amdgcn_rcpf(1.0f + __builtin_amdgcn_exp2f(-_pre)); \
    const float _act = fmaf(aA1, _s1, aB1); \
    const float _fv = DPPF(_act, 0x55); \
    const float _gv = DPPF(_act, 0xAA); \
    const float _ov = DPPF(_act, 0xFF); \
    c1r = fmaf(_fv, c1r, _act * _gv);        /* valid on T1==0 (act = i there) */ \
    h1r = _ov * tanh_c(c1r);                 /* valid on T1==0 */ \
} while (0)

#define LSTM2_STEP(RG, TT) do { \
    const float4 _rq = *(const float4*)&h1l[RG][TT][4 * s2]; \
    const float2 _r01 = make_float2(fmaxf(_rq.x, 0.f), fmaxf(_rq.y, 0.f)); \
    const float2 _r23 = make_float2(fmaxf(_rq.z, 0.f), fmaxf(_rq.w, 0.f)); \
    float2 _a2 = pkfma(w2a, _r01, make_float2(bias2l, w2h * h2s)); \
    _a2 = pkfma(w2b, _r23, _a2); \
    float _p2 = _a2.x + _a2.y; \
    _p2 += DPPF(_p2, 0xB1); \
    _p2 += DPPF(_p2, 0x4E); \
    const float _act2 = fmaf(aA2, \
        __builtin_amdgcn_rcpf(1.0f + __builtin_amdgcn_exp2f(-_p2)), aB2); \
    const float _fv2 = SWZF(_act2, 0x101F); \
    const float _gv2 = SWZF(_act2, 0x201F); \
    const float _ov2 = SWZF(_act2, 0x301F); \
    c2r = fmaf(_fv2, c2r, _act2 * _gv2);     /* valid on T2==0 */ \
    h2v = _ov2 * tanh_c(c2r); \
    h2s = BPERM(ahs, h2v); \
} while (0)

    // ---- pre-loop: wave1 stages chunk0's xg, prefetches chunk1 ----
    if (wid == 1) {
        LOADX(0);
        MFMA_XG(0);
        LOADX(1);
    }
    __syncthreads();

    for (int c = 0; c < NB; ++c) {
        if (wid == 0) {
            const float* xrow = &xgl[c & 1][0];
            const int rg = c & 1;
#pragma unroll
            for (int tt = 0; tt < TB; ++tt) {
                const float xu = xrow[tt * XSTR + gidx];
                STEP1(xu);
                if (T1 == 0) h1l[rg][tt][j1] = h1r;
            }
        } else {
            if (c + 1 < NB) {
                bf16x8 a0s = make_frag(xpf[0], xpf[1]);
                bf16x8 a1s = make_frag(xpf[2], xpf[3]);
                if (c + 2 < NB) LOADX(c + 2);
#pragma unroll
                for (int n = 0; n < 4; ++n) {
                    f32x4 acc = {bias1[n], bias1[n], bias1[n], bias1[n]};
                    acc = __builtin_amdgcn_mfma_f32_16x16x32_bf16(a0s, wb[n][0], acc, 0, 0, 0);
                    acc = __builtin_amdgcn_mfma_f32_16x16x32_bf16(a1s, wb[n][1], acc, 0, 0, 0);
#pragma unroll
                    for (int r = 0; r < 4; ++r)
                        xgl[(c + 1) & 1][(kh * 4 + r) * XSTR + n * 16 + tl] = acc[r];
                }
            }
            if (c >= 1) {
                const int rg = (c - 1) & 1;
#pragma unroll
                for (int tt = 0; tt < TB; ++tt)
                    LSTM2_STEP(rg, tt);
            }
        }
        __syncthreads();
    }

    // ---- tail: wave1 finishes LSTM2 chunk NB-1, then FC + sigmoid ----
    if (wid == 1) {
        const int rg = (NB - 1) & 1;
#pragma unroll
        for (int tt = 0; tt < TB; ++tt)
            LSTM2_STEP(rg, tt);

        const float hq0 = __shfl(h2v, 0);    // h2[m] valid on lanes 16m (T2==0)
        const float hq1 = __shfl(h2v, 16);
        const float hq2 = __shfl(h2v, 32);
        const float hq3 = __shfl(h2v, 48);
        float accf = bfcv;
        accf = fmaf(wfc.x, hq0, accf);
        accf = fmaf(wfc.y, hq1, accf);
        accf = fmaf(wfc.z, hq2, accf);
        accf = fmaf(wfc.w, hq3, accf);
        out[b * 64 + lane] = fsigm(accf);
    }
#undef LOADX
#undef MFMA_XG
#undef STEP1
#undef LSTM2_STEP
}

extern "C" void kernel_launch(void* const* d_in, const int* in_sizes, int n_in,
                              void* d_out, int out_size, void* d_ws, size_t ws_size,
                              hipStream_t stream) {
    const float* x    = (const float*)d_in[0];
    const float* Wih1 = (const float*)d_in[1];
    const float* Whh1 = (const float*)d_in[2];
    const float* bih1 = (const float*)d_in[3];
    const float* bhh1 = (const float*)d_in[4];
    const float* Wih2 = (const float*)d_in[5];
    const float* Whh2 = (const float*)d_in[6];
    const float* bih2 = (const float*)d_in[7];
    const float* bhh2 = (const float*)d_in[8];
    const float* Wfc  = (const float*)d_in[9];
    const float* bfc  = (const float*)d_in[10];
    float* out = (float*)d_out;

    lstm_fused_v8<<<dim3(2048), dim3(128), 0, stream>>>(
        x, Wih1, Whh1, bih1, bhh1, Wih2, Whh2, bih2, bhh2, Wfc, bfc, out);
}